// Round 6
// baseline (2212.441 us; speedup 1.0000x reference)
//
#include <hip/hip_runtime.h>
#include <hip/hip_bf16.h>
#include <hip/hip_cooperative_groups.h>
#include <math.h>

namespace cg = cooperative_groups;

typedef __bf16 bf16_t;
typedef bf16_t bf16x8 __attribute__((ext_vector_type(8)));
typedef float f32x4 __attribute__((ext_vector_type(4)));

#define T_SEQ 128
#define NB 32
#define NV 32000
#define NE 512
#define NH 1024
#define G4 4096          // 4*NH
#define MROWS 4064       // 127*32
#define MPAD 4096

// async global->LDS, 16B per lane, wave-uniform LDS base
__device__ __forceinline__ void g2lds16(const bf16_t* g, bf16_t* l) {
  __builtin_amdgcn_global_load_lds((const __attribute__((address_space(1))) void*)g,
                                   (__attribute__((address_space(3))) void*)l, 16, 0, 0);
}

__device__ __forceinline__ unsigned short bf16bits(float x) {
  bf16_t b = (bf16_t)x;
  return __builtin_bit_cast(unsigned short, b);
}

// ---------------- prep: casts, gather, zeroing ----------------
__global__ void k_prep(const int* __restrict__ idx, const float* __restrict__ emb,
                       const float* __restrict__ W_ih, const float* __restrict__ W_hh,
                       const float* __restrict__ b_ih, const float* __restrict__ b_hh,
                       const float* __restrict__ W_out, const float* __restrict__ h0,
                       bf16_t* __restrict__ W_ih_bf, bf16_t* __restrict__ W_hh_bf,
                       bf16_t* __restrict__ W_out_bf, bf16_t* __restrict__ x_bf,
                       bf16_t* __restrict__ h_all, bf16_t* __restrict__ h0_bf,
                       float* __restrict__ bc, float* __restrict__ rowS,
                       int* __restrict__ tgt, unsigned* __restrict__ bar) {
  const long nW_ih = 4096L * 512;
  const long nW_hh = 4096L * 1024;
  const long nW_out = 32000L * 1024;
  const long nX = 4096L * 512;
  const long nH0 = 32L * 1024;
  const long nHpad = 32L * 1024;
  const long NTOTAL = nW_ih + nW_hh + nW_out + nX + nH0 + nHpad + 3 * 4096L + 1024;
  long stride = (long)gridDim.x * blockDim.x;
  for (long i = (long)blockIdx.x * blockDim.x + threadIdx.x; i < NTOTAL; i += stride) {
    long j = i;
    if (j < nW_ih) { W_ih_bf[j] = (bf16_t)W_ih[j]; continue; }
    j -= nW_ih;
    if (j < nW_hh) { W_hh_bf[j] = (bf16_t)W_hh[j]; continue; }
    j -= nW_hh;
    if (j < nW_out) { W_out_bf[j] = (bf16_t)W_out[j]; continue; }
    j -= nW_out;
    if (j < nX) {
      long m = j >> 9; int e = (int)(j & 511);
      float x = 0.f;
      if (m < MROWS) { x = emb[(long)idx[m] * NE + e]; x = x > 0.f ? x : 0.f; }
      x_bf[j] = (bf16_t)x; continue;
    }
    j -= nX;
    if (j < nH0) { h0_bf[j] = (bf16_t)h0[j]; continue; }
    j -= nH0;
    if (j < nHpad) { h_all[4161536L + j] = (bf16_t)0.f; continue; }  // pad rows 4064..4095
    j -= nHpad;
    if (j < 4096) { bc[j] = b_ih[j] + b_hh[j]; continue; }
    j -= 4096;
    if (j < 4096) { rowS[j] = 0.f; continue; }
    j -= 4096;
    if (j < 4096) { tgt[j] = (j < MROWS) ? idx[j + NB] : 0; continue; }
    j -= 4096;
    { bar[j] = 0u; continue; }
  }
}

// ---------------- GEMM1: gates = x @ W_ih^T + (b_ih+b_hh), interleaved bf16 out --------
// Output layout: gates_xi[row][unit*4 + gate]  (gate: 0=i,1=f,2=g,3=o)
__global__ __launch_bounds__(256) void k_gemm1(const bf16_t* __restrict__ A,
                                               const bf16_t* __restrict__ B,
                                               const float* __restrict__ bc,
                                               bf16_t* __restrict__ C) {
  const int K = 512;
  int tid = threadIdx.x, wid = tid >> 6, lane = tid & 63;
  int wm = wid & 1, wn = wid >> 1;
  int quad = lane >> 4, l15 = lane & 15;
  int mBase = blockIdx.x * 64, nBase = blockIdx.y * 128;

  const bf16x8* pa0 = (const bf16x8*)(A + (long)(mBase + wm * 32 + l15) * K + quad * 8);
  const bf16x8* pa1 = (const bf16x8*)(A + (long)(mBase + wm * 32 + 16 + l15) * K + quad * 8);
  const bf16x8* pb[4];
#pragma unroll
  for (int j = 0; j < 4; ++j)
    pb[j] = (const bf16x8*)(B + (long)(nBase + wn * 64 + j * 16 + l15) * K + quad * 8);

  f32x4 acc[2][4];
#pragma unroll
  for (int mi = 0; mi < 2; ++mi)
#pragma unroll
    for (int ni = 0; ni < 4; ++ni) acc[mi][ni] = (f32x4){0.f, 0.f, 0.f, 0.f};

  for (int kk = 0; kk < K / 32; ++kk) {
    bf16x8 a0 = pa0[kk * 4], a1 = pa1[kk * 4];
    bf16x8 b0 = pb[0][kk * 4], b1 = pb[1][kk * 4], b2 = pb[2][kk * 4], b3 = pb[3][kk * 4];
    acc[0][0] = __builtin_amdgcn_mfma_f32_16x16x32_bf16(a0, b0, acc[0][0], 0, 0, 0);
    acc[0][1] = __builtin_amdgcn_mfma_f32_16x16x32_bf16(a0, b1, acc[0][1], 0, 0, 0);
    acc[0][2] = __builtin_amdgcn_mfma_f32_16x16x32_bf16(a0, b2, acc[0][2], 0, 0, 0);
    acc[0][3] = __builtin_amdgcn_mfma_f32_16x16x32_bf16(a0, b3, acc[0][3], 0, 0, 0);
    acc[1][0] = __builtin_amdgcn_mfma_f32_16x16x32_bf16(a1, b0, acc[1][0], 0, 0, 0);
    acc[1][1] = __builtin_amdgcn_mfma_f32_16x16x32_bf16(a1, b1, acc[1][1], 0, 0, 0);
    acc[1][2] = __builtin_amdgcn_mfma_f32_16x16x32_bf16(a1, b2, acc[1][2], 0, 0, 0);
    acc[1][3] = __builtin_amdgcn_mfma_f32_16x16x32_bf16(a1, b3, acc[1][3], 0, 0, 0);
  }
#pragma unroll
  for (int ni = 0; ni < 4; ++ni) {
    int col = nBase + wn * 64 + ni * 16 + l15;
    float bcv = bc[col];
    int colI = ((col & 1023) << 2) | (col >> 10);  // interleave: unit*4 + gate
#pragma unroll
    for (int mi = 0; mi < 2; ++mi)
#pragma unroll
      for (int r = 0; r < 4; ++r) {
        int row = mBase + wm * 32 + mi * 16 + quad * 4 + r;
        C[(long)row * G4 + colI] = (bf16_t)(acc[mi][ni][r] + bcv);
      }
  }
}

// ---------------- LSTM recurrence v5: per-wave flat barrier, no LDS/syncthreads -------
// 128 blocks x 256 threads (4 waves). Wave = 16 batch rows x (4 units x 4 gates), full K.
// Barrier: wave stores step count to its own slot (write-through), polls all 256 slots
// of its batch-half (one dword/lane x4 + ballot). One coherence hop, no RMW.
__global__ __launch_bounds__(256) void k_rec5(const bf16_t* __restrict__ gates_xi,
                                              const bf16_t* __restrict__ W_hh_bf,
                                              const bf16_t* __restrict__ h0_bf,
                                              bf16_t* __restrict__ h_all,
                                              const float* __restrict__ c0,
                                              unsigned* __restrict__ bar) {
  int bid = blockIdx.x;
  int mi = bid & 1;            // batch half
  int ub = bid >> 1;           // unit block (16 units)
  int tid = threadIdx.x, wid = tid >> 6, lane = tid & 63;
  int quad = lane >> 4, l15 = lane & 15;
  int u = l15 >> 2, g = l15 & 3;
  int ubase = ub * 16 + wid * 4;   // first unit of this wave
  int unit = ubase + u;

  // B-fragment base: W_hh row = gate*1024 + unit
  const bf16x8* pb = (const bf16x8*)(W_hh_bf + ((long)(g << 10) + unit) * NH + quad * 8);

  float cst[4];
#pragma unroll
  for (int r = 0; r < 4; ++r)
    cst[r] = c0[(long)(mi * 16 + quad * 4 + r) * NH + unit];

  unsigned* slots = bar + mi * 256;          // this half's 256 wave-slots
  unsigned* myslot = slots + ub * 4 + wid;

  for (int t = 0; t < T_SEQ - 1; ++t) {
    // gates prefetch (independent of h; overlaps the poll)
    const unsigned short* gxp = (const unsigned short*)gates_xi +
        (long)(t * NB + mi * 16 + quad * 4) * G4 + ub * 64 + wid * 16 + l15;
    unsigned short gxr[4];
#pragma unroll
    for (int r = 0; r < 4; ++r) gxr[r] = gxp[(long)r * G4];

    if (t > 0) {
      unsigned tv = (unsigned)t;
      for (;;) {
        unsigned s0 = __hip_atomic_load(&slots[lane * 4 + 0], __ATOMIC_RELAXED, __HIP_MEMORY_SCOPE_AGENT);
        unsigned s1 = __hip_atomic_load(&slots[lane * 4 + 1], __ATOMIC_RELAXED, __HIP_MEMORY_SCOPE_AGENT);
        unsigned s2 = __hip_atomic_load(&slots[lane * 4 + 2], __ATOMIC_RELAXED, __HIP_MEMORY_SCOPE_AGENT);
        unsigned s3 = __hip_atomic_load(&slots[lane * 4 + 3], __ATOMIC_RELAXED, __HIP_MEMORY_SCOPE_AGENT);
        bool ok = (s0 >= tv) && (s1 >= tv) && (s2 >= tv) && (s3 >= tv);
        if (__ballot(ok) == ~0ull) break;
        __builtin_amdgcn_s_sleep(1);
      }
    }

    const bf16_t* hp = (t == 0) ? h0_bf : (h_all + (long)(t - 1) * NB * NH);
    const bf16x8* pa = (const bf16x8*)(hp + (long)(mi * 16 + l15) * NH + quad * 8);
    f32x4 ac0 = (f32x4){0.f, 0.f, 0.f, 0.f};
    f32x4 ac1 = (f32x4){0.f, 0.f, 0.f, 0.f};
    f32x4 ac2 = (f32x4){0.f, 0.f, 0.f, 0.f};
    f32x4 ac3 = (f32x4){0.f, 0.f, 0.f, 0.f};
#pragma unroll
    for (int kk = 0; kk < 32; kk += 4) {  // 4 interleaved chains, dep depth 8
      ac0 = __builtin_amdgcn_mfma_f32_16x16x32_bf16(pa[(kk + 0) * 4], pb[(kk + 0) * 4], ac0, 0, 0, 0);
      ac1 = __builtin_amdgcn_mfma_f32_16x16x32_bf16(pa[(kk + 1) * 4], pb[(kk + 1) * 4], ac1, 0, 0, 0);
      ac2 = __builtin_amdgcn_mfma_f32_16x16x32_bf16(pa[(kk + 2) * 4], pb[(kk + 2) * 4], ac2, 0, 0, 0);
      ac3 = __builtin_amdgcn_mfma_f32_16x16x32_bf16(pa[(kk + 3) * 4], pb[(kk + 3) * 4], ac3, 0, 0, 0);
    }
    f32x4 acc = (ac0 + ac1) + (ac2 + ac3);

    long orow = (long)(t * NB + mi * 16) * NH;
#pragma unroll
    for (int r = 0; r < 4; ++r) {
      unsigned gb = ((unsigned)gxr[r]) << 16;
      float v = acc[r] + __builtin_bit_cast(float, gb);
      float vi = v;                       // lane l15%4==0 holds i; neighbors f,g,o
      float vf = __shfl_xor(v, 1);
      float vg = __shfl_xor(v, 2);
      float vo = __shfl_xor(v, 3);
      float si = 1.f / (1.f + __expf(-vi));
      float sf = 1.f / (1.f + __expf(-vf));
      float so = 1.f / (1.f + __expf(-vo));
      float tg2 = 1.f - 2.f / (__expf(2.f * vg) + 1.f);
      float cs = sf * cst[r] + si * tg2;
      cst[r] = cs;
      float th = 1.f - 2.f / (__expf(2.f * cs) + 1.f);
      float hh = so * th;
      unsigned hb = (unsigned)bf16bits(hh);
      unsigned x4 = (unsigned)__shfl_xor((int)hb, 4);
      unsigned pk = hb | (x4 << 16);
      unsigned x8 = (unsigned)__shfl_xor((int)pk, 8);
      if (l15 == 0) {
        unsigned long long v8 = (unsigned long long)pk | ((unsigned long long)x8 << 32);
        __hip_atomic_store(
            (unsigned long long*)(h_all + orow + (long)(quad * 4 + r) * NH + ubase),
            v8, __ATOMIC_RELAXED, __HIP_MEMORY_SCOPE_AGENT);
      }
    }

    if (t < T_SEQ - 2) {
      __builtin_amdgcn_s_waitcnt(0);  // h stores acked at coherence point
      if (lane == 0)
        __hip_atomic_store(myslot, (unsigned)(t + 1), __ATOMIC_RELAXED,
                           __HIP_MEMORY_SCOPE_AGENT);
    }
  }
}

// ---------------- GEMM2: m97-style LDS-staged, exp-rowsum epilogue ----------------
__global__ __launch_bounds__(256) void k_gemm2(const bf16_t* __restrict__ A,
                                               const bf16_t* __restrict__ B,
                                               const float* __restrict__ b_out,
                                               float* __restrict__ rowS) {
  __shared__ bf16_t As[128 * 32];
  __shared__ bf16_t Bs[128 * 32];
  const int K = 1024;
  int tid = threadIdx.x, wid = tid >> 6, lane = tid & 63;
  int wm = wid & 1, wn = wid >> 1;
  int quad = lane >> 4, l15 = lane & 15;
  int mBase = blockIdx.x * 128, nBase = blockIdx.y * 128;

  int rc = lane >> 2, seg = lane & 3;
  int cA0 = 2 * wid, cA1 = 2 * wid + 1;
  const bf16_t* gA0 = A + (size_t)(mBase + cA0 * 16 + rc) * K + seg * 8;
  const bf16_t* gA1 = A + (size_t)(mBase + cA1 * 16 + rc) * K + seg * 8;
  const bf16_t* gB0 = B + (size_t)(nBase + cA0 * 16 + rc) * K + seg * 8;
  const bf16_t* gB1 = B + (size_t)(nBase + cA1 * 16 + rc) * K + seg * 8;
  bf16_t* lA0 = As + cA0 * 512;
  bf16_t* lA1 = As + cA1 * 512;
  bf16_t* lB0 = Bs + cA0 * 512;
  bf16_t* lB1 = Bs + cA1 * 512;

  const bf16x8* pa[4];
  const bf16x8* pbf[4];
#pragma unroll
  for (int i = 0; i < 4; ++i) {
    pa[i] = (const bf16x8*)(As + (wm * 64 + i * 16 + l15) * 32 + quad * 8);
    pbf[i] = (const bf16x8*)(Bs + (wn * 64 + i * 16 + l15) * 32 + quad * 8);
  }

  f32x4 acc[4][4];
#pragma unroll
  for (int i = 0; i < 4; ++i)
#pragma unroll
    for (int j = 0; j < 4; ++j) acc[i][j] = (f32x4){0.f, 0.f, 0.f, 0.f};

  for (int kt = 0; kt < K / 32; ++kt) {
    g2lds16(gA0 + kt * 32, lA0);
    g2lds16(gA1 + kt * 32, lA1);
    g2lds16(gB0 + kt * 32, lB0);
    g2lds16(gB1 + kt * 32, lB1);
    __syncthreads();

    bf16x8 af[4], bf[4];
#pragma unroll
    for (int i = 0; i < 4; ++i) { af[i] = *pa[i]; bf[i] = *pbf[i]; }
#pragma unroll
    for (int i = 0; i < 4; ++i)
#pragma unroll
      for (int j = 0; j < 4; ++j)
        acc[i][j] = __builtin_amdgcn_mfma_f32_16x16x32_bf16(af[i], bf[j], acc[i][j], 0, 0, 0);
    __syncthreads();
  }

#pragma unroll
  for (int i = 0; i < 4; ++i) {
    float rs[4] = {0.f, 0.f, 0.f, 0.f};
#pragma unroll
    for (int j = 0; j < 4; ++j) {
      int col = nBase + wn * 64 + j * 16 + l15;
      float bb = b_out[col];
#pragma unroll
      for (int r = 0; r < 4; ++r) rs[r] += __expf(acc[i][j][r] + bb);
    }
#pragma unroll
    for (int r = 0; r < 4; ++r) {
#pragma unroll
      for (int s = 1; s < 16; s <<= 1) rs[r] += __shfl_xor(rs[r], s);
      if (l15 == 0) {
        int row = mBase + wm * 64 + i * 16 + quad * 4 + r;
        if (row < MROWS) atomicAdd(&rowS[row], rs[r]);
      }
    }
  }
}

// ---------------- target logits ----------------
__global__ __launch_bounds__(256) void k_tgt(const bf16_t* __restrict__ h_all,
                                             const bf16_t* __restrict__ W_out_bf,
                                             const float* __restrict__ b_out,
                                             const int* __restrict__ tgt,
                                             float* __restrict__ tgt_logit) {
  int gw = (int)((blockIdx.x * blockDim.x + threadIdx.x) >> 6);
  int lane = threadIdx.x & 63;
  if (gw >= MROWS) return;
  int v = tgt[gw];
  const bf16x8* ph = (const bf16x8*)(h_all + (long)gw * NH + lane * 16);
  const bf16x8* pw = (const bf16x8*)(W_out_bf + (long)v * NH + lane * 16);
  float acc = 0.f;
#pragma unroll
  for (int j = 0; j < 2; ++j) {
    bf16x8 h8 = ph[j], w8 = pw[j];
#pragma unroll
    for (int q = 0; q < 8; ++q) acc += (float)h8[q] * (float)w8[q];
  }
#pragma unroll
  for (int s = 1; s < 64; s <<= 1) acc += __shfl_xor(acc, s);
  if (lane == 0) tgt_logit[gw] = acc + b_out[v];
}

// ---------------- final loss reduction ----------------
__global__ __launch_bounds__(256) void k_loss(const float* __restrict__ rowS,
                                              const float* __restrict__ tl,
                                              const int* __restrict__ tgt,
                                              float* __restrict__ out) {
  __shared__ float sm[256];
  float s = 0.f;
  for (int i = threadIdx.x; i < MROWS; i += 256)
    if (tgt[i] != 0) s += logf(rowS[i]) - tl[i];
  sm[threadIdx.x] = s;
  __syncthreads();
  for (int off = 128; off > 0; off >>= 1) {
    if (threadIdx.x < off) sm[threadIdx.x] += sm[threadIdx.x + off];
    __syncthreads();
  }
  if (threadIdx.x == 0) out[0] = sm[0];
}

extern "C" void kernel_launch(void* const* d_in, const int* in_sizes, int n_in,
                              void* d_out, int out_size, void* d_ws, size_t ws_size,
                              hipStream_t stream) {
  const int* idx = (const int*)d_in[0];
  const float* emb = (const float*)d_in[1];
  const float* W_ih = (const float*)d_in[2];
  const float* W_hh = (const float*)d_in[3];
  const float* b_ih = (const float*)d_in[4];
  const float* b_hh = (const float*)d_in[5];
  const float* W_out = (const float*)d_in[6];
  const float* b_out = (const float*)d_in[7];
  const float* h0 = (const float*)d_in[8];
  const float* c0 = (const float*)d_in[9];

  char* ws = (char*)d_ws;
  bf16_t* W_ih_bf = (bf16_t*)ws;            ws += 4096L * 512 * 2;
  bf16_t* W_hh_bf = (bf16_t*)ws;            ws += 4096L * 1024 * 2;
  bf16_t* W_out_bf = (bf16_t*)ws;           ws += 32000L * 1024 * 2;
  bf16_t* x_bf = (bf16_t*)ws;               ws += 4096L * 512 * 2;
  bf16_t* gates_xi = (bf16_t*)ws;           ws += 4096L * 4096 * 2;
  bf16_t* h_all = (bf16_t*)ws;              ws += 4096L * 1024 * 2;
  bf16_t* h0_bf = (bf16_t*)ws;              ws += 32L * 1024 * 2;
  float* bc = (float*)ws;                   ws += 4096L * 4;
  float* rowS = (float*)ws;                 ws += 4096L * 4;
  float* tgt_logit = (float*)ws;            ws += 4096L * 4;
  int* tgt = (int*)ws;                      ws += 4096L * 4;
  unsigned* bar = (unsigned*)ws;            ws += 1024L * 4;

  k_prep<<<4096, 256, 0, stream>>>(idx, emb, W_ih, W_hh, b_ih, b_hh, W_out, h0,
                                   W_ih_bf, W_hh_bf, W_out_bf, x_bf, h_all, h0_bf,
                                   bc, rowS, tgt, bar);

  k_gemm1<<<dim3(64, 32), 256, 0, stream>>>(x_bf, W_ih_bf, bc, gates_xi);

  {
    void* args[] = {(void*)&gates_xi, (void*)&W_hh_bf, (void*)&h0_bf, (void*)&h_all,
                    (void*)&c0, (void*)&bar};
    hipLaunchCooperativeKernel((void*)k_rec5, dim3(128), dim3(256), args, 0, stream);
  }

  k_gemm2<<<dim3(32, 250), 256, 0, stream>>>(h_all, W_out_bf, b_out, rowS);

  k_tgt<<<1016, 256, 0, stream>>>(h_all, W_out_bf, b_out, tgt, tgt_logit);

  k_loss<<<1, 256, 0, stream>>>(rowS, tgt_logit, tgt, (float*)d_out);
}

// Round 7
// 1455.395 us; speedup vs baseline: 1.5202x; 1.5202x over previous
//
#include <hip/hip_runtime.h>
#include <hip/hip_bf16.h>
#include <hip/hip_cooperative_groups.h>
#include <math.h>

namespace cg = cooperative_groups;

typedef __bf16 bf16_t;
typedef bf16_t bf16x8 __attribute__((ext_vector_type(8)));
typedef float f32x4 __attribute__((ext_vector_type(4)));

#define T_SEQ 128
#define NB 32
#define NV 32000
#define NE 512
#define NH 1024
#define G4 4096          // 4*NH
#define MROWS 4064       // 127*32
#define MPAD 4096

// async global->LDS, 16B per lane, wave-uniform LDS base
__device__ __forceinline__ void g2lds16(const bf16_t* g, bf16_t* l) {
  __builtin_amdgcn_global_load_lds((const __attribute__((address_space(1))) void*)g,
                                   (__attribute__((address_space(3))) void*)l, 16, 0, 0);
}

__device__ __forceinline__ unsigned short bf16bits(float x) {
  bf16_t b = (bf16_t)x;
  return __builtin_bit_cast(unsigned short, b);
}

// ---------------- prep: casts, gather, zeroing ----------------
__global__ void k_prep(const int* __restrict__ idx, const float* __restrict__ emb,
                       const float* __restrict__ W_ih, const float* __restrict__ W_hh,
                       const float* __restrict__ b_ih, const float* __restrict__ b_hh,
                       const float* __restrict__ W_out, const float* __restrict__ h0,
                       bf16_t* __restrict__ W_ih_bf, bf16_t* __restrict__ W_hh_bf,
                       bf16_t* __restrict__ W_out_bf, bf16_t* __restrict__ x_bf,
                       bf16_t* __restrict__ h_all, bf16_t* __restrict__ h0_bf,
                       float* __restrict__ bc, float* __restrict__ rowS,
                       int* __restrict__ tgt, unsigned* __restrict__ bar) {
  const long nW_ih = 4096L * 512;
  const long nW_hh = 4096L * 1024;
  const long nW_out = 32000L * 1024;
  const long nX = 4096L * 512;
  const long nH0 = 32L * 1024;
  const long nHpad = 32L * 1024;
  const long NTOTAL = nW_ih + nW_hh + nW_out + nX + nH0 + nHpad + 3 * 4096L + 1024;
  long stride = (long)gridDim.x * blockDim.x;
  for (long i = (long)blockIdx.x * blockDim.x + threadIdx.x; i < NTOTAL; i += stride) {
    long j = i;
    if (j < nW_ih) { W_ih_bf[j] = (bf16_t)W_ih[j]; continue; }
    j -= nW_ih;
    if (j < nW_hh) { W_hh_bf[j] = (bf16_t)W_hh[j]; continue; }
    j -= nW_hh;
    if (j < nW_out) { W_out_bf[j] = (bf16_t)W_out[j]; continue; }
    j -= nW_out;
    if (j < nX) {
      long m = j >> 9; int e = (int)(j & 511);
      float x = 0.f;
      if (m < MROWS) { x = emb[(long)idx[m] * NE + e]; x = x > 0.f ? x : 0.f; }
      x_bf[j] = (bf16_t)x; continue;
    }
    j -= nX;
    if (j < nH0) { h0_bf[j] = (bf16_t)h0[j]; continue; }
    j -= nH0;
    if (j < nHpad) { h_all[4161536L + j] = (bf16_t)0.f; continue; }  // pad rows 4064..4095
    j -= nHpad;
    if (j < 4096) { bc[j] = b_ih[j] + b_hh[j]; continue; }
    j -= 4096;
    if (j < 4096) { rowS[j] = 0.f; continue; }
    j -= 4096;
    if (j < 4096) { tgt[j] = (j < MROWS) ? idx[j + NB] : 0; continue; }
    j -= 4096;
    { bar[j] = 0u; continue; }
  }
}

// ---------------- GEMM1: gates_x = x @ W_ih^T + (b_ih+b_hh), bf16 out ----------------
__global__ __launch_bounds__(256) void k_gemm1(const bf16_t* __restrict__ A,
                                               const bf16_t* __restrict__ B,
                                               const float* __restrict__ bc,
                                               bf16_t* __restrict__ C) {
  const int K = 512;
  int tid = threadIdx.x, wid = tid >> 6, lane = tid & 63;
  int wm = wid & 1, wn = wid >> 1;
  int quad = lane >> 4, l15 = lane & 15;
  int mBase = blockIdx.x * 64, nBase = blockIdx.y * 128;

  const bf16x8* pa0 = (const bf16x8*)(A + (long)(mBase + wm * 32 + l15) * K + quad * 8);
  const bf16x8* pa1 = (const bf16x8*)(A + (long)(mBase + wm * 32 + 16 + l15) * K + quad * 8);
  const bf16x8* pb[4];
#pragma unroll
  for (int j = 0; j < 4; ++j)
    pb[j] = (const bf16x8*)(B + (long)(nBase + wn * 64 + j * 16 + l15) * K + quad * 8);

  f32x4 acc[2][4];
#pragma unroll
  for (int mi = 0; mi < 2; ++mi)
#pragma unroll
    for (int ni = 0; ni < 4; ++ni) acc[mi][ni] = (f32x4){0.f, 0.f, 0.f, 0.f};

  for (int kk = 0; kk < K / 32; ++kk) {
    bf16x8 a0 = pa0[kk * 4], a1 = pa1[kk * 4];
    bf16x8 b0 = pb[0][kk * 4], b1 = pb[1][kk * 4], b2 = pb[2][kk * 4], b3 = pb[3][kk * 4];
    acc[0][0] = __builtin_amdgcn_mfma_f32_16x16x32_bf16(a0, b0, acc[0][0], 0, 0, 0);
    acc[0][1] = __builtin_amdgcn_mfma_f32_16x16x32_bf16(a0, b1, acc[0][1], 0, 0, 0);
    acc[0][2] = __builtin_amdgcn_mfma_f32_16x16x32_bf16(a0, b2, acc[0][2], 0, 0, 0);
    acc[0][3] = __builtin_amdgcn_mfma_f32_16x16x32_bf16(a0, b3, acc[0][3], 0, 0, 0);
    acc[1][0] = __builtin_amdgcn_mfma_f32_16x16x32_bf16(a1, b0, acc[1][0], 0, 0, 0);
    acc[1][1] = __builtin_amdgcn_mfma_f32_16x16x32_bf16(a1, b1, acc[1][1], 0, 0, 0);
    acc[1][2] = __builtin_amdgcn_mfma_f32_16x16x32_bf16(a1, b2, acc[1][2], 0, 0, 0);
    acc[1][3] = __builtin_amdgcn_mfma_f32_16x16x32_bf16(a1, b3, acc[1][3], 0, 0, 0);
  }
#pragma unroll
  for (int ni = 0; ni < 4; ++ni) {
    int col = nBase + wn * 64 + ni * 16 + l15;
    float bcv = bc[col];
#pragma unroll
    for (int mi = 0; mi < 2; ++mi)
#pragma unroll
      for (int r = 0; r < 4; ++r) {
        int row = mBase + wm * 32 + mi * 16 + quad * 4 + r;
        C[(long)row * G4 + col] = (bf16_t)(acc[mi][ni][r] + bcv);
      }
  }
}

// ---------------- LSTM recurrence v6: rec4 structure + flat slot barrier -------------
// 256 blocks x 512 threads; block = (8 units) x (batch half of 16); 8 waves:
// (cg: i/f vs g/o) x (kh: K-quarter). W_hh VGPR-resident. Barrier: per-block slot
// store (write-through) + wave0 poll of 128 slots + LDS go release. One syncthreads.
__global__ __launch_bounds__(512) void k_rec6(const bf16_t* __restrict__ gates_x,
                                              const bf16_t* __restrict__ W_hh_bf,
                                              const bf16_t* __restrict__ h0_bf,
                                              bf16_t* __restrict__ h_all,
                                              const float* __restrict__ c0,
                                              unsigned* __restrict__ bar) {
  __shared__ float red[2 * 16 * 16 * 4];  // [cg][b(16)][col(16)][kh(4)] f32
  __shared__ unsigned go;

  int bid = blockIdx.x;
  int mi = bid & 1;              // batch half
  int hb = bid >> 1;             // 0..127 within half
  int gbase = hb * 8;            // first hidden unit owned by this block
  int tid = threadIdx.x, wid = tid >> 6, lane = tid & 63;
  int cg = wid & 1, kh = wid >> 1;
  int quad = lane >> 4, l15 = lane & 15;

  int wrow = (cg ? 2048 : 0) + ((l15 & 8) ? 1024 : 0) + gbase + (l15 & 7);
  const bf16x8* pw = (const bf16x8*)(W_hh_bf + (long)wrow * NH + kh * 256 + quad * 8);
  bf16x8 wfrag[8];
#pragma unroll
  for (int kk = 0; kk < 8; ++kk) wfrag[kk] = pw[kk * 4];  // resident in VGPRs

  unsigned* slots = bar + mi * 128;  // one slot per block of this half

  // pointwise: threads 0..63 (wave 0): b = tid>>2, unit pair = (tid&3)*2
  int pb = tid >> 2, pu2 = (tid & 3) * 2;
  int u0 = gbase + pu2;
  int bglob = mi * 16 + pb;
  float cst0 = 0.f, cst1 = 0.f;
  if (tid < 64) {
    cst0 = c0[(long)bglob * NH + u0];
    cst1 = c0[(long)bglob * NH + u0 + 1];
  }
  unsigned* h32 = (unsigned*)h_all;

  if (tid == 0) go = 0;
  __syncthreads();

  for (int t = 0; t < T_SEQ - 1; ++t) {
    // gates prefetch for pointwise (wave 0 only; overlaps the poll)
    unsigned gxi2 = 0, gxf2 = 0, gxg2 = 0, gxo2 = 0;
    if (wid == 0) {
      const unsigned* gp = (const unsigned*)(gates_x + (long)(t * NB + bglob) * G4);
      int q = u0 >> 1;
      gxi2 = gp[q]; gxf2 = gp[512 + q]; gxg2 = gp[1024 + q]; gxo2 = gp[1536 + q];
    }

    if (t > 0) {
      unsigned tv = (unsigned)t;
      if (wid == 0) {
        for (;;) {
          unsigned s0 = __hip_atomic_load(&slots[lane], __ATOMIC_RELAXED,
                                          __HIP_MEMORY_SCOPE_AGENT);
          unsigned s1 = __hip_atomic_load(&slots[64 + lane], __ATOMIC_RELAXED,
                                          __HIP_MEMORY_SCOPE_AGENT);
          if (__ballot((s0 >= tv) && (s1 >= tv)) == ~0ull) break;
          __builtin_amdgcn_s_sleep(1);
        }
        if (lane == 0)
          __hip_atomic_store(&go, tv, __ATOMIC_RELAXED, __HIP_MEMORY_SCOPE_WORKGROUP);
      } else {
        while (__hip_atomic_load(&go, __ATOMIC_RELAXED, __HIP_MEMORY_SCOPE_WORKGROUP) < tv)
          __builtin_amdgcn_s_sleep(1);
      }
    }

    const bf16_t* hp = (t == 0) ? h0_bf : (h_all + (long)(t - 1) * NB * NH);
    const bf16x8* pa = (const bf16x8*)(hp + (long)(mi * 16 + l15) * NH + kh * 256 + quad * 8);
    f32x4 acc = (f32x4){0.f, 0.f, 0.f, 0.f};
#pragma unroll
    for (int kk = 0; kk < 8; ++kk) {
      bf16x8 a = pa[kk * 4];
      acc = __builtin_amdgcn_mfma_f32_16x16x32_bf16(a, wfrag[kk], acc, 0, 0, 0);
    }
#pragma unroll
    for (int r = 0; r < 4; ++r) {
      int b = quad * 4 + r;
      red[(((cg << 4) + b) << 6) + (l15 << 2) + kh] = acc[r];
    }
    __syncthreads();  // red[] complete for this step

    if (tid < 64) {
      const float4* rp = (const float4*)red;
      float hv[2];
#pragma unroll
      for (int d = 0; d < 2; ++d) {
        int q = pu2 + d;
        float4 vi = rp[(pb << 4) + q];
        float4 vf = rp[(pb << 4) + 8 + q];
        float4 vg = rp[((16 + pb) << 4) + q];
        float4 vo = rp[((16 + pb) << 4) + 8 + q];
        unsigned bi = d ? (gxi2 & 0xffff0000u) : (gxi2 << 16);
        unsigned bff = d ? (gxf2 & 0xffff0000u) : (gxf2 << 16);
        unsigned bg = d ? (gxg2 & 0xffff0000u) : (gxg2 << 16);
        unsigned bo = d ? (gxo2 & 0xffff0000u) : (gxo2 << 16);
        float iv = vi.x + vi.y + vi.z + vi.w + __builtin_bit_cast(float, bi);
        float fv = vf.x + vf.y + vf.z + vf.w + __builtin_bit_cast(float, bff);
        float gv = vg.x + vg.y + vg.z + vg.w + __builtin_bit_cast(float, bg);
        float ov = vo.x + vo.y + vo.z + vo.w + __builtin_bit_cast(float, bo);
        float si = 1.f / (1.f + __expf(-iv));
        float sf = 1.f / (1.f + __expf(-fv));
        float so = 1.f / (1.f + __expf(-ov));
        float tg = 1.f - 2.f / (__expf(2.f * gv) + 1.f);
        float& cs = d ? cst1 : cst0;
        cs = sf * cs + si * tg;
        float th = 1.f - 2.f / (__expf(2.f * cs) + 1.f);
        hv[d] = so * th;
      }
      unsigned pack = (unsigned)bf16bits(hv[0]) | ((unsigned)bf16bits(hv[1]) << 16);
      __hip_atomic_store(&h32[(long)(t * NB + bglob) * 512 + (u0 >> 1)], pack,
                         __ATOMIC_RELAXED, __HIP_MEMORY_SCOPE_AGENT);
    }

    if (t < T_SEQ - 2 && wid == 0) {
      __builtin_amdgcn_s_waitcnt(0x0f70);  // vmcnt(0): h stores acked at LLC
      if (lane == 0)
        __hip_atomic_store(&slots[hb], (unsigned)(t + 1), __ATOMIC_RELAXED,
                           __HIP_MEMORY_SCOPE_AGENT);
    }
  }
}

// ---------------- GEMM2: m97-style LDS-staged, exp-rowsum epilogue ----------------
__global__ __launch_bounds__(256) void k_gemm2(const bf16_t* __restrict__ A,
                                               const bf16_t* __restrict__ B,
                                               const float* __restrict__ b_out,
                                               float* __restrict__ rowS) {
  __shared__ bf16_t As[128 * 32];
  __shared__ bf16_t Bs[128 * 32];
  const int K = 1024;
  int tid = threadIdx.x, wid = tid >> 6, lane = tid & 63;
  int wm = wid & 1, wn = wid >> 1;
  int quad = lane >> 4, l15 = lane & 15;
  int mBase = blockIdx.x * 128, nBase = blockIdx.y * 128;

  int rc = lane >> 2, seg = lane & 3;
  int cA0 = 2 * wid, cA1 = 2 * wid + 1;
  const bf16_t* gA0 = A + (size_t)(mBase + cA0 * 16 + rc) * K + seg * 8;
  const bf16_t* gA1 = A + (size_t)(mBase + cA1 * 16 + rc) * K + seg * 8;
  const bf16_t* gB0 = B + (size_t)(nBase + cA0 * 16 + rc) * K + seg * 8;
  const bf16_t* gB1 = B + (size_t)(nBase + cA1 * 16 + rc) * K + seg * 8;
  bf16_t* lA0 = As + cA0 * 512;
  bf16_t* lA1 = As + cA1 * 512;
  bf16_t* lB0 = Bs + cA0 * 512;
  bf16_t* lB1 = Bs + cA1 * 512;

  const bf16x8* pa[4];
  const bf16x8* pbf[4];
#pragma unroll
  for (int i = 0; i < 4; ++i) {
    pa[i] = (const bf16x8*)(As + (wm * 64 + i * 16 + l15) * 32 + quad * 8);
    pbf[i] = (const bf16x8*)(Bs + (wn * 64 + i * 16 + l15) * 32 + quad * 8);
  }

  f32x4 acc[4][4];
#pragma unroll
  for (int i = 0; i < 4; ++i)
#pragma unroll
    for (int j = 0; j < 4; ++j) acc[i][j] = (f32x4){0.f, 0.f, 0.f, 0.f};

  for (int kt = 0; kt < K / 32; ++kt) {
    g2lds16(gA0 + kt * 32, lA0);
    g2lds16(gA1 + kt * 32, lA1);
    g2lds16(gB0 + kt * 32, lB0);
    g2lds16(gB1 + kt * 32, lB1);
    __syncthreads();

    bf16x8 af[4], bf[4];
#pragma unroll
    for (int i = 0; i < 4; ++i) { af[i] = *pa[i]; bf[i] = *pbf[i]; }
#pragma unroll
    for (int i = 0; i < 4; ++i)
#pragma unroll
      for (int j = 0; j < 4; ++j)
        acc[i][j] = __builtin_amdgcn_mfma_f32_16x16x32_bf16(af[i], bf[j], acc[i][j], 0, 0, 0);
    __syncthreads();
  }

#pragma unroll
  for (int i = 0; i < 4; ++i) {
    float rs[4] = {0.f, 0.f, 0.f, 0.f};
#pragma unroll
    for (int j = 0; j < 4; ++j) {
      int col = nBase + wn * 64 + j * 16 + l15;
      float bb = b_out[col];
#pragma unroll
      for (int r = 0; r < 4; ++r) rs[r] += __expf(acc[i][j][r] + bb);
    }
#pragma unroll
    for (int r = 0; r < 4; ++r) {
#pragma unroll
      for (int s = 1; s < 16; s <<= 1) rs[r] += __shfl_xor(rs[r], s);
      if (l15 == 0) {
        int row = mBase + wm * 64 + i * 16 + quad * 4 + r;
        if (row < MROWS) atomicAdd(&rowS[row], rs[r]);
      }
    }
  }
}

// ---------------- target logits ----------------
__global__ __launch_bounds__(256) void k_tgt(const bf16_t* __restrict__ h_all,
                                             const bf16_t* __restrict__ W_out_bf,
                                             const float* __restrict__ b_out,
                                             const int* __restrict__ tgt,
                                             float* __restrict__ tgt_logit) {
  int gw = (int)((blockIdx.x * blockDim.x + threadIdx.x) >> 6);
  int lane = threadIdx.x & 63;
  if (gw >= MROWS) return;
  int v = tgt[gw];
  const bf16x8* ph = (const bf16x8*)(h_all + (long)gw * NH + lane * 16);
  const bf16x8* pw = (const bf16x8*)(W_out_bf + (long)v * NH + lane * 16);
  float acc = 0.f;
#pragma unroll
  for (int j = 0; j < 2; ++j) {
    bf16x8 h8 = ph[j], w8 = pw[j];
#pragma unroll
    for (int q = 0; q < 8; ++q) acc += (float)h8[q] * (float)w8[q];
  }
#pragma unroll
  for (int s = 1; s < 64; s <<= 1) acc += __shfl_xor(acc, s);
  if (lane == 0) tgt_logit[gw] = acc + b_out[v];
}

// ---------------- final loss reduction ----------------
__global__ __launch_bounds__(256) void k_loss(const float* __restrict__ rowS,
                                              const float* __restrict__ tl,
                                              const int* __restrict__ tgt,
                                              float* __restrict__ out) {
  __shared__ float sm[256];
  float s = 0.f;
  for (int i = threadIdx.x; i < MROWS; i += 256)
    if (tgt[i] != 0) s += logf(rowS[i]) - tl[i];
  sm[threadIdx.x] = s;
  __syncthreads();
  for (int off = 128; off > 0; off >>= 1) {
    if (threadIdx.x < off) sm[threadIdx.x] += sm[threadIdx.x + off];
    __syncthreads();
  }
  if (threadIdx.x == 0) out[0] = sm[0];
}

extern "C" void kernel_launch(void* const* d_in, const int* in_sizes, int n_in,
                              void* d_out, int out_size, void* d_ws, size_t ws_size,
                              hipStream_t stream) {
  const int* idx = (const int*)d_in[0];
  const float* emb = (const float*)d_in[1];
  const float* W_ih = (const float*)d_in[2];
  const float* W_hh = (const float*)d_in[3];
  const float* b_ih = (const float*)d_in[4];
  const float* b_hh = (const float*)d_in[5];
  const float* W_out = (const float*)d_in[6];
  const float* b_out = (const float*)d_in[7];
  const float* h0 = (const float*)d_in[8];
  const float* c0 = (const float*)d_in[9];

  char* ws = (char*)d_ws;
  bf16_t* W_ih_bf = (bf16_t*)ws;            ws += 4096L * 512 * 2;
  bf16_t* W_hh_bf = (bf16_t*)ws;            ws += 4096L * 1024 * 2;
  bf16_t* W_out_bf = (bf16_t*)ws;           ws += 32000L * 1024 * 2;
  bf16_t* x_bf = (bf16_t*)ws;               ws += 4096L * 512 * 2;
  bf16_t* gates_x = (bf16_t*)ws;            ws += 4096L * 4096 * 2;
  bf16_t* h_all = (bf16_t*)ws;              ws += 4096L * 1024 * 2;
  bf16_t* h0_bf = (bf16_t*)ws;              ws += 32L * 1024 * 2;
  float* bc = (float*)ws;                   ws += 4096L * 4;
  float* rowS = (float*)ws;                 ws += 4096L * 4;
  float* tgt_logit = (float*)ws;            ws += 4096L * 4;
  int* tgt = (int*)ws;                      ws += 4096L * 4;
  unsigned* bar = (unsigned*)ws;            ws += 1024L * 4;

  k_prep<<<4096, 256, 0, stream>>>(idx, emb, W_ih, W_hh, b_ih, b_hh, W_out, h0,
                                   W_ih_bf, W_hh_bf, W_out_bf, x_bf, h_all, h0_bf,
                                   bc, rowS, tgt, bar);

  k_gemm1<<<dim3(64, 32), 256, 0, stream>>>(x_bf, W_ih_bf, bc, gates_x);

  {
    void* args[] = {(void*)&gates_x, (void*)&W_hh_bf, (void*)&h0_bf, (void*)&h_all,
                    (void*)&c0, (void*)&bar};
    hipLaunchCooperativeKernel((void*)k_rec6, dim3(256), dim3(512), args, 0, stream);
  }

  k_gemm2<<<dim3(32, 250), 256, 0, stream>>>(h_all, W_out_bf, b_out, rowS);

  k_tgt<<<1016, 256, 0, stream>>>(h_all, W_out_bf, b_out, tgt, tgt_logit);

  k_loss<<<1, 256, 0, stream>>>(rowS, tgt_logit, tgt, (float*)d_out);
}